// Round 8
// baseline (487.153 us; speedup 1.0000x reference)
//
#include <hip/hip_runtime.h>
#include <hip/hip_bf16.h>
#include <stdint.h>

typedef __attribute__((ext_vector_type(8)))  short    short8;
typedef __attribute__((ext_vector_type(16))) float    floatx16;
typedef __attribute__((ext_vector_type(4)))  float    floatx4;
typedef __attribute__((ext_vector_type(4)))  uint32_t uint4v;

#define B_    64
#define CIN   64
#define COUT  128
#define T_    300
#define V_    25
#define NRED  (B_ * T_ * V_)     // 480000 elements per channel
#define NSLOTS 32
#define NT    12                 // t's per block; 300/12 = 25 chunks; groups of 4
#define EPS   1e-5f

__device__ __forceinline__ uint32_t pk2(float a, float b) {
    union { __hip_bfloat162 h; uint32_t u; } c;
    c.h = __float22bfloat162_rn(make_float2(a, b));
    return c.u;
}

__device__ __forceinline__ floatx16 fzero16() {
    floatx16 z;
#pragma unroll
    for (int i = 0; i < 16; ++i) z[i] = 0.f;
    return z;
}

// magic division by 25, valid for 0 <= n < 2048
__device__ __forceinline__ int div25(int n) { return (n * 5243) >> 17; }

// Barrier that drains ONLY LDS ops (T4: keep global loads/stores in flight).
// __syncthreads would force vmcnt(0): every tile would serialize on the ack
// of 13 flush stores + 8 prefetch loads.  Cross-wave correctness needs only
// lgkmcnt(0): my ds_writes complete before I signal; all waves' ds_reads of
// the outgoing buffer also drained (lgkmcnt counts reads) before entry.
__device__ __forceinline__ void lgkm_barrier() {
    __builtin_amdgcn_sched_barrier(0);
    asm volatile("s_waitcnt lgkmcnt(0)" ::: "memory");
    __builtin_amdgcn_s_barrier();
    __builtin_amdgcn_sched_barrier(0);
}

// Hᵀ C-layout -> B-fragment layout via lane^32 half-wave swap (verified R2/R3).
__device__ __forceinline__ void cvt_hb(const floatx16 h, int q, short8 hb[2]) {
    uint32_t pk[8], pp[8];
#pragma unroll
    for (int i = 0; i < 8; ++i) pk[i] = pk2(h[2 * i], h[2 * i + 1]);
#pragma unroll
    for (int i = 0; i < 8; ++i) pp[i] = (uint32_t)__shfl_xor((int)pk[i], 32, 64);
#pragma unroll
    for (int s = 0; s < 2; ++s) {
        union { short8 sv; uint32_t u[4]; } F;
        F.u[0] = q ? pp[4 * s + 2] : pk[4 * s];
        F.u[1] = q ? pp[4 * s + 3] : pk[4 * s + 1];
        F.u[2] = q ? pk[4 * s + 2] : pp[4 * s];
        F.u[3] = q ? pk[4 * s + 3] : pp[4 * s + 1];
        hb[s] = F.sv;
    }
}

// Per-block constant fragments (verified R3):
//  wf[kk]: Wᵀ B-frag  B[k=c=16kk+8q+j][n=o=32*wave+ln] = W[o][c]
//  af[s] : adjᵀ A-frag A[m=w=ln][k=v=16s+8q+j]         = adj[v][w] (zero-padded)
__device__ __forceinline__ void build_const_frags(const float* __restrict__ W,
                                                  const float* __restrict__ adj,
                                                  int wave, int ln, int q,
                                                  short8 wf[4], short8 af[2]) {
    const float* wr = W + (32 * wave + ln) * CIN;
#pragma unroll
    for (int kk = 0; kk < 4; ++kk) {
        int c0 = 16 * kk + 8 * q;
        floatx4 a = *(const floatx4*)(wr + c0);
        floatx4 b = *(const floatx4*)(wr + c0 + 4);
        union { short8 sv; uint32_t u[4]; } F;
        F.u[0] = pk2(a[0], a[1]); F.u[1] = pk2(a[2], a[3]);
        F.u[2] = pk2(b[0], b[1]); F.u[3] = pk2(b[2], b[3]);
        wf[kk] = F.sv;
    }
#pragma unroll
    for (int s = 0; s < 2; ++s) {
        union { short8 sv; uint32_t u[4]; } F;
#pragma unroll
        for (int p = 0; p < 4; ++p) {
            int v0 = 16 * s + 8 * q + 2 * p;
            float e0 = (v0     < V_ && ln < V_) ? adj[v0 * V_ + ln]       : 0.f;
            float e1 = (v0 + 1 < V_ && ln < V_) ? adj[(v0 + 1) * V_ + ln] : 0.f;
            F.u[p] = pk2(e0, e1);
        }
        af[s] = F.sv;
    }
}

// ---- COALESCED pipelined staging (verified R7) -----------------------------
// pc = div25(cid), ch = cid - 25*pc: consecutive lanes -> consecutive 16B
// chunks of row 2pc (and 2pc+1): fully coalesced 400B segments.
// LDS layout: u32 lds[tv][32], cpair pc at 16B-granule (pc>>2)^s, s = ch&7
// (== (tv>>2)&7): commit spreads over 8 bank-groups, frag reads ~4-way.
__device__ __forceinline__ void stage_issue(const float* __restrict__ xb, int t4,
                                            int tid, floatx4 a[4], floatx4 b[4]) {
#pragma unroll
    for (int i = 0; i < 4; ++i) {
        int cid = i * 256 + tid;
        if (i < 3 || tid < 32) {
            int pc = div25(cid);          // c-pair 0..31
            int ch = cid - 25 * pc;       // t-chunk 0..24
            const float* p0 = xb + (2 * pc) * 7500 + t4 * 25 + 4 * ch;
            a[i] = *(const floatx4*)p0;
            b[i] = *(const floatx4*)(p0 + 7500);
        }
    }
}

__device__ __forceinline__ void stage_commit(uint32_t* __restrict__ lds, int tid,
                                             const floatx4 a[4], const floatx4 b[4]) {
#pragma unroll
    for (int i = 0; i < 4; ++i) {
        int cid = i * 256 + tid;
        if (i < 3 || tid < 32) {
            int pc = div25(cid);
            int ch = cid - 25 * pc;
            const int g = pc >> 2;
            const int c2 = pc & 3;
            const int s = ch & 7;         // == (tv>>2)&7 for tv = 4ch+k
#pragma unroll
            for (int k = 0; k < 4; ++k) {
                int tv = 4 * ch + k;
                lds[tv * 32 + (((g ^ s) << 2) | c2)] = pk2(a[i][k], b[i][k]);
            }
        }
    }
}

// Xᵀ A-frags from transposed LDS: 4 x ds_read_b128, zero repack VALU.
__device__ __forceinline__ void build_xa_ldsT(const uint32_t* __restrict__ lds,
                                              int tloc, int vcl, int q, short8 xa[4]) {
    const int tv = tloc * 25 + vcl;
    const uint32_t* row = lds + tv * 32;
    const int s = (tv >> 2) & 7;
#pragma unroll
    for (int kk = 0; kk < 4; ++kk) {
        union { short8 sv; uint4v u4; } F;
        F.u4 = *(const uint4v*)(row + (((q + 2 * kk) ^ s) << 2));
        xa[kk] = F.sv;
    }
}

// Yᵀ for one t (verified R3): Hᵀ = Xᵀ·Wᵀ (K=64), cvt, Yᵀ = adjᵀ·Hᵀ (K=32).
// C-layout: lane -> channel o (col), regs -> w rows; w>=25 exactly 0.
__device__ __forceinline__ floatx16 compute_yt(const short8 xa[4], const short8 wf[4],
                                               const short8 af[2], int q) {
    floatx16 h = fzero16();
#pragma unroll
    for (int kk = 0; kk < 4; ++kk)
        h = __builtin_amdgcn_mfma_f32_32x32x16_bf16(xa[kk], wf[kk], h, 0, 0, 0);
    short8 hb[2];
    cvt_hb(h, q, hb);
    floatx16 y = fzero16();
#pragma unroll
    for (int s = 0; s < 2; ++s)
        y = __builtin_amdgcn_mfma_f32_32x32x16_bf16(af[s], hb[s], y, 0, 0, 0);
    return y;
}

// ---- pass 1: per-channel sum / sumsq partials ------------------------------
// occ 4 (25.6 KB LDS, VGPR < 128): +33% TLP vs R7's 3.
__global__ __launch_bounds__(256, 4) void pass1_kernel(
    const float* __restrict__ x, const float* __restrict__ adj,
    const float* __restrict__ W,
    float* __restrict__ psum, float* __restrict__ psq)
{
    __shared__ __attribute__((aligned(16))) uint32_t bufA[3200];
    __shared__ __attribute__((aligned(16))) uint32_t bufB[3200];

    const int tid  = threadIdx.x;
    const int wave = tid >> 6;
    const int lane = tid & 63;
    const int q    = lane >> 5;
    const int ln   = lane & 31;
    const int b    = blockIdx.y;
    const int tbase = blockIdx.x * NT;

    short8 wf[4], af[2];
    build_const_frags(W, adj, wave, ln, q, wf, af);
    const int vcl = ln < V_ ? ln : V_ - 1;   // clamp: garbage rows killed by af zero-pad
    const float* xb = x + (size_t)b * (CIN * T_ * V_);

    floatx4 sa[4], sb[4];
    stage_issue(xb, tbase, tid, sa, sb);
    stage_commit(bufA, tid, sa, sb);
    lgkm_barrier();
    uint32_t* cur = bufA;
    uint32_t* nxt = bufB;

    float sum = 0.f, sq = 0.f;
    for (int g = 0; g < NT / 4; ++g) {
        if (g < NT / 4 - 1) stage_issue(xb, tbase + 4 * (g + 1), tid, sa, sb);
        __builtin_amdgcn_sched_barrier(0);   // keep next-tile loads above compute
#pragma unroll
        for (int tloc = 0; tloc < 4; ++tloc) {
            short8 xa[4];
            build_xa_ldsT(cur, tloc, vcl, q, xa);
            floatx16 y = compute_yt(xa, wf, af, q);
#pragma unroll
            for (int r = 0; r < 16; ++r) { sum += y[r]; sq += y[r] * y[r]; }
        }
        if (g < NT / 4 - 1) {
            stage_commit(nxt, tid, sa, sb);  // loads landed under compute
            lgkm_barrier();
            uint32_t* t = cur; cur = nxt; nxt = t;
        }
    }

    // channel o=32*wave+ln lives in lanes l and l^32
    sum += __shfl_xor(sum, 32, 64);
    sq  += __shfl_xor(sq,  32, 64);
    if (q == 0) {
        int slot = (blockIdx.y * 25 + blockIdx.x) & (NSLOTS - 1);
        atomicAdd(&psum[slot * COUT + 32 * wave + ln], sum);
        atomicAdd(&psq [slot * COUT + 32 * wave + ln], sq);
    }
}

// ---- pass 2: R7 pipeline + lgkm-only barriers ------------------------------
__global__ __launch_bounds__(256, 2) void pass2_kernel(
    const float* __restrict__ x, const float* __restrict__ adj,
    const float* __restrict__ W,
    const float* __restrict__ gamma, const float* __restrict__ beta,
    const float* __restrict__ psum, const float* __restrict__ psq,
    float* __restrict__ out)
{
    __shared__ __attribute__((aligned(16))) uint32_t bufA[3200];
    __shared__ __attribute__((aligned(16))) uint32_t bufB[3200];
    __shared__ __attribute__((aligned(16))) float ldso[4][3200];

    const int tid  = threadIdx.x;
    const int wave = tid >> 6;
    const int lane = tid & 63;
    const int q    = lane >> 5;
    const int ln   = lane & 31;
    const int b    = blockIdx.y;
    const int tbase = blockIdx.x * NT;
    const int o_l  = 32 * wave + ln;

    short8 wf[4], af[2];
    build_const_frags(W, adj, wave, ln, q, wf, af);

    // fold the 32 partial slots -> per-lane scale/shift
    float s = 0.f, ss = 0.f;
#pragma unroll 4
    for (int k = 0; k < NSLOTS; ++k) {
        s  += psum[k * COUT + o_l];
        ss += psq [k * COUT + o_l];
    }
    const float mean = s / (float)NRED;
    const float var  = ss / (float)NRED - mean * mean;
    const float inv  = rsqrtf(var + EPS);
    const float sc   = gamma[o_l] * inv;
    const float sh   = beta[o_l] - mean * sc;

    const int vcl = ln < V_ ? ln : V_ - 1;
    const float* xb = x + (size_t)b * (CIN * T_ * V_);
    float* const ob = out + (size_t)(b * COUT + 32 * wave) * (T_ * V_);

    floatx4 sa[4], sb[4];
    stage_issue(xb, tbase, tid, sa, sb);
    stage_commit(bufA, tid, sa, sb);
    lgkm_barrier();
    uint32_t* cur = bufA;
    uint32_t* nxt = bufB;

    for (int g = 0; g < NT / 4; ++g) {
        const int t4 = tbase + 4 * g;
        if (g < NT / 4 - 1) stage_issue(xb, tbase + 4 * (g + 1), tid, sa, sb);
        __builtin_amdgcn_sched_barrier(0);   // keep next-tile loads above compute

        float* const ow0 = &ldso[wave][ln * 100];
#pragma unroll
        for (int tloc = 0; tloc < 4; ++tloc) {
            short8 xa[4];
            build_xa_ldsT(cur, tloc, vcl, q, xa);
            floatx16 y = compute_yt(xa, wf, af, q);
            // stage relu'd values: [o=ln][tloc*25 + w], w = 4q + 8g2 + j
            float* ow = ow0 + tloc * 25 + 4 * q;
#pragma unroll
            for (int g2 = 0; g2 < 3; ++g2) {
#pragma unroll
                for (int j = 0; j < 4; ++j) {
                    float v = sc * y[4 * g2 + j] + sh;
                    ow[8 * g2 + j] = v > 0.f ? v : 0.f;
                }
            }
            if (q == 0) {                      // w = 24  (reg 12)
                float v = sc * y[12] + sh;
                ow0[tloc * 25 + 24] = v > 0.f ? v : 0.f;
            }
        }

        if (g < NT / 4 - 1) {
            stage_commit(nxt, tid, sa, sb);  // loads landed under compute
            lgkm_barrier();
        }

        // flush this wave's 32o x 100 floats: 13 coalesced 16B-aligned dwordx4.
        // After the lgkm barrier: stores stay in flight across ALL barriers
        // now (no vmcnt drain anywhere in the loop) and retire under the
        // next tile's compute.  ldso reads are own-wave, program-ordered.
#pragma unroll
        for (int f = 0; f < 13; ++f) {
            int cid = f * 64 + lane;
            if (f < 12 || lane < 32) {
                int o = div25(cid);
                int c = cid - 25 * o;
                floatx4 v = *(const floatx4*)&ldso[wave][o * 100 + 4 * c];
                *(floatx4*)(ob + (size_t)o * (T_ * V_) + t4 * 25 + 4 * c) = v;
            }
        }

        uint32_t* t = cur; cur = nxt; nxt = t;
    }
}

// ---- stats are folded inside pass2; nothing else needed --------------------

extern "C" void kernel_launch(void* const* d_in, const int* in_sizes, int n_in,
                              void* d_out, int out_size, void* d_ws, size_t ws_size,
                              hipStream_t stream) {
    const float* x     = (const float*)d_in[0];
    const float* adj   = (const float*)d_in[1];
    const float* W     = (const float*)d_in[2];
    // d_in[3] = conv bias: cancelled exactly by training-mode BatchNorm -> unused
    const float* gamma = (const float*)d_in[4];
    const float* beta  = (const float*)d_in[5];
    float* out = (float*)d_out;

    float* psum = (float*)d_ws;
    float* psq  = (float*)((char*)d_ws + NSLOTS * COUT * sizeof(float));

    hipMemsetAsync(psum, 0, 2 * NSLOTS * COUT * sizeof(float), stream);

    dim3 grid(T_ / NT, B_);
    pass1_kernel<<<grid, 256, 0, stream>>>(x, adj, W, psum, psq);
    pass2_kernel<<<grid, 256, 0, stream>>>(x, adj, W, gamma, beta, psum, psq, out);
}

// Round 9
// 434.930 us; speedup vs baseline: 1.1201x; 1.1201x over previous
//
#include <hip/hip_runtime.h>
#include <hip/hip_bf16.h>
#include <stdint.h>

typedef __attribute__((ext_vector_type(8)))  short    short8;
typedef __attribute__((ext_vector_type(16))) float    floatx16;
typedef __attribute__((ext_vector_type(4)))  float    floatx4;
typedef __attribute__((ext_vector_type(4)))  uint32_t uint4v;

#define B_    64
#define CIN   64
#define COUT  128
#define T_    300
#define V_    25
#define NRED  (B_ * T_ * V_)     // 480000 elements per channel
#define NSLOTS 32
#define NT    12                 // t's per block; 300/12 = 25 chunks; groups of 4
#define EPS   1e-5f

__device__ __forceinline__ uint32_t pk2(float a, float b) {
    union { __hip_bfloat162 h; uint32_t u; } c;
    c.h = __float22bfloat162_rn(make_float2(a, b));
    return c.u;
}

__device__ __forceinline__ floatx16 fzero16() {
    floatx16 z;
#pragma unroll
    for (int i = 0; i < 16; ++i) z[i] = 0.f;
    return z;
}

// magic division by 25, valid for 0 <= n < 2048
__device__ __forceinline__ int div25(int n) { return (n * 5243) >> 17; }

// Hᵀ C-layout -> B-fragment layout via lane^32 half-wave swap (verified R2/R3).
__device__ __forceinline__ void cvt_hb(const floatx16 h, int q, short8 hb[2]) {
    uint32_t pk[8], pp[8];
#pragma unroll
    for (int i = 0; i < 8; ++i) pk[i] = pk2(h[2 * i], h[2 * i + 1]);
#pragma unroll
    for (int i = 0; i < 8; ++i) pp[i] = (uint32_t)__shfl_xor((int)pk[i], 32, 64);
#pragma unroll
    for (int s = 0; s < 2; ++s) {
        union { short8 sv; uint32_t u[4]; } F;
        F.u[0] = q ? pp[4 * s + 2] : pk[4 * s];
        F.u[1] = q ? pp[4 * s + 3] : pk[4 * s + 1];
        F.u[2] = q ? pk[4 * s + 2] : pp[4 * s];
        F.u[3] = q ? pk[4 * s + 3] : pp[4 * s + 1];
        hb[s] = F.sv;
    }
}

// Per-block constant fragments (verified R3):
//  wf[kk]: Wᵀ B-frag  B[k=c=16kk+8q+j][n=o=32*wave+ln] = W[o][c]
//  af[s] : adjᵀ A-frag A[m=w=ln][k=v=16s+8q+j]         = adj[v][w] (zero-padded)
__device__ __forceinline__ void build_const_frags(const float* __restrict__ W,
                                                  const float* __restrict__ adj,
                                                  int wave, int ln, int q,
                                                  short8 wf[4], short8 af[2]) {
    const float* wr = W + (32 * wave + ln) * CIN;
#pragma unroll
    for (int kk = 0; kk < 4; ++kk) {
        int c0 = 16 * kk + 8 * q;
        floatx4 a = *(const floatx4*)(wr + c0);
        floatx4 b = *(const floatx4*)(wr + c0 + 4);
        union { short8 sv; uint32_t u[4]; } F;
        F.u[0] = pk2(a[0], a[1]); F.u[1] = pk2(a[2], a[3]);
        F.u[2] = pk2(b[0], b[1]); F.u[3] = pk2(b[2], b[3]);
        wf[kk] = F.sv;
    }
#pragma unroll
    for (int s = 0; s < 2; ++s) {
        union { short8 sv; uint32_t u[4]; } F;
#pragma unroll
        for (int p = 0; p < 4; ++p) {
            int v0 = 16 * s + 8 * q + 2 * p;
            float e0 = (v0     < V_ && ln < V_) ? adj[v0 * V_ + ln]       : 0.f;
            float e1 = (v0 + 1 < V_ && ln < V_) ? adj[(v0 + 1) * V_ + ln] : 0.f;
            F.u[p] = pk2(e0, e1);
        }
        af[s] = F.sv;
    }
}

// ---- COALESCED pipelined staging (verified R7) -----------------------------
// pc = div25(cid), ch = cid - 25*pc: consecutive lanes -> consecutive 16B
// chunks of row 2pc (and 2pc+1): fully coalesced 400B segments.
// LDS layout: u32 lds[tv][32], cpair pc at 16B-granule (pc>>2)^s, s = ch&7
// (== (tv>>2)&7): commit spreads over 8 bank-groups, frag reads ~4-way.
__device__ __forceinline__ void stage_issue(const float* __restrict__ xb, int t4,
                                            int tid, floatx4 a[4], floatx4 b[4]) {
#pragma unroll
    for (int i = 0; i < 4; ++i) {
        int cid = i * 256 + tid;
        if (i < 3 || tid < 32) {
            int pc = div25(cid);          // c-pair 0..31
            int ch = cid - 25 * pc;       // t-chunk 0..24
            const float* p0 = xb + (2 * pc) * 7500 + t4 * 25 + 4 * ch;
            a[i] = *(const floatx4*)p0;
            b[i] = *(const floatx4*)(p0 + 7500);
        }
    }
}

__device__ __forceinline__ void stage_commit(uint32_t* __restrict__ lds, int tid,
                                             const floatx4 a[4], const floatx4 b[4]) {
#pragma unroll
    for (int i = 0; i < 4; ++i) {
        int cid = i * 256 + tid;
        if (i < 3 || tid < 32) {
            int pc = div25(cid);
            int ch = cid - 25 * pc;
            const int g = pc >> 2;
            const int c2 = pc & 3;
            const int s = ch & 7;         // == (tv>>2)&7 for tv = 4ch+k
#pragma unroll
            for (int k = 0; k < 4; ++k) {
                int tv = 4 * ch + k;
                lds[tv * 32 + (((g ^ s) << 2) | c2)] = pk2(a[i][k], b[i][k]);
            }
        }
    }
}

// Xᵀ A-frags from transposed LDS: 4 x ds_read_b128, zero repack VALU.
__device__ __forceinline__ void build_xa_ldsT(const uint32_t* __restrict__ lds,
                                              int tloc, int vcl, int q, short8 xa[4]) {
    const int tv = tloc * 25 + vcl;
    const uint32_t* row = lds + tv * 32;
    const int s = (tv >> 2) & 7;
#pragma unroll
    for (int kk = 0; kk < 4; ++kk) {
        union { short8 sv; uint4v u4; } F;
        F.u4 = *(const uint4v*)(row + (((q + 2 * kk) ^ s) << 2));
        xa[kk] = F.sv;
    }
}

// Yᵀ for one t (verified R3): Hᵀ = Xᵀ·Wᵀ (K=64), cvt, Yᵀ = adjᵀ·Hᵀ (K=32).
// C-layout: lane -> channel o (col), regs -> w rows; w>=25 exactly 0.
__device__ __forceinline__ floatx16 compute_yt(const short8 xa[4], const short8 wf[4],
                                               const short8 af[2], int q) {
    floatx16 h = fzero16();
#pragma unroll
    for (int kk = 0; kk < 4; ++kk)
        h = __builtin_amdgcn_mfma_f32_32x32x16_bf16(xa[kk], wf[kk], h, 0, 0, 0);
    short8 hb[2];
    cvt_hb(h, q, hb);
    floatx16 y = fzero16();
#pragma unroll
    for (int s = 0; s < 2; ++s)
        y = __builtin_amdgcn_mfma_f32_32x32x16_bf16(af[s], hb[s], y, 0, 0, 0);
    return y;
}

// ---- pass 1: per-channel sum / sumsq partials (R4 structure) ---------------
__global__ __launch_bounds__(256, 3) void pass1_kernel(
    const float* __restrict__ x, const float* __restrict__ adj,
    const float* __restrict__ W,
    float* __restrict__ psum, float* __restrict__ psq)
{
    __shared__ __attribute__((aligned(16))) uint32_t bufA[3200];
    __shared__ __attribute__((aligned(16))) uint32_t bufB[3200];

    const int tid  = threadIdx.x;
    const int wave = tid >> 6;
    const int lane = tid & 63;
    const int q    = lane >> 5;
    const int ln   = lane & 31;
    const int b    = blockIdx.y;
    const int tbase = blockIdx.x * NT;

    short8 wf[4], af[2];
    build_const_frags(W, adj, wave, ln, q, wf, af);
    const int vcl = ln < V_ ? ln : V_ - 1;   // clamp: garbage rows killed by af zero-pad
    const float* xb = x + (size_t)b * (CIN * T_ * V_);

    floatx4 sa[4], sb[4];
    stage_issue(xb, tbase, tid, sa, sb);
    stage_commit(bufA, tid, sa, sb);
    __syncthreads();
    uint32_t* cur = bufA;
    uint32_t* nxt = bufB;

    float sum = 0.f, sq = 0.f;
    for (int g = 0; g < NT / 4; ++g) {
        if (g < NT / 4 - 1) stage_issue(xb, tbase + 4 * (g + 1), tid, sa, sb);
        __builtin_amdgcn_sched_barrier(0);   // keep next-tile loads above compute
#pragma unroll
        for (int tloc = 0; tloc < 4; ++tloc) {
            short8 xa[4];
            build_xa_ldsT(cur, tloc, vcl, q, xa);
            floatx16 y = compute_yt(xa, wf, af, q);
#pragma unroll
            for (int r = 0; r < 16; ++r) { sum += y[r]; sq += y[r] * y[r]; }
        }
        if (g < NT / 4 - 1) {
            stage_commit(nxt, tid, sa, sb);  // loads landed under compute
            __syncthreads();
            uint32_t* t = cur; cur = nxt; nxt = t;
        }
    }

    // channel o=32*wave+ln lives in lanes l and l^32
    sum += __shfl_xor(sum, 32, 64);
    sq  += __shfl_xor(sq,  32, 64);
    if (q == 0) {
        int slot = (blockIdx.y * 25 + blockIdx.x) & (NSLOTS - 1);
        atomicAdd(&psum[slot * COUT + 32 * wave + ln], sum);
        atomicAdd(&psq [slot * COUT + 32 * wave + ln], sq);
    }
}

// ---- pass 2: R4 pipeline + deferred dwordx4 flush (proven best epilogue) ---
__global__ __launch_bounds__(256, 2) void pass2_kernel(
    const float* __restrict__ x, const float* __restrict__ adj,
    const float* __restrict__ W,
    const float* __restrict__ gamma, const float* __restrict__ beta,
    const float* __restrict__ psum, const float* __restrict__ psq,
    float* __restrict__ out)
{
    __shared__ __attribute__((aligned(16))) uint32_t bufA[3200];
    __shared__ __attribute__((aligned(16))) uint32_t bufB[3200];
    __shared__ __attribute__((aligned(16))) float ldso[4][3200];

    const int tid  = threadIdx.x;
    const int wave = tid >> 6;
    const int lane = tid & 63;
    const int q    = lane >> 5;
    const int ln   = lane & 31;
    const int b    = blockIdx.y;
    const int tbase = blockIdx.x * NT;
    const int o_l  = 32 * wave + ln;

    short8 wf[4], af[2];
    build_const_frags(W, adj, wave, ln, q, wf, af);

    // fold the 32 partial slots -> per-lane scale/shift
    float s = 0.f, ss = 0.f;
#pragma unroll 4
    for (int k = 0; k < NSLOTS; ++k) {
        s  += psum[k * COUT + o_l];
        ss += psq [k * COUT + o_l];
    }
    const float mean = s / (float)NRED;
    const float var  = ss / (float)NRED - mean * mean;
    const float inv  = rsqrtf(var + EPS);
    const float sc   = gamma[o_l] * inv;
    const float sh   = beta[o_l] - mean * sc;

    const int vcl = ln < V_ ? ln : V_ - 1;
    const float* xb = x + (size_t)b * (CIN * T_ * V_);
    float* const ob = out + (size_t)(b * COUT + 32 * wave) * (T_ * V_);

    floatx4 sa[4], sb[4];
    stage_issue(xb, tbase, tid, sa, sb);
    stage_commit(bufA, tid, sa, sb);
    __syncthreads();
    uint32_t* cur = bufA;
    uint32_t* nxt = bufB;

    for (int g = 0; g < NT / 4; ++g) {
        const int t4 = tbase + 4 * g;
        if (g < NT / 4 - 1) stage_issue(xb, tbase + 4 * (g + 1), tid, sa, sb);
        __builtin_amdgcn_sched_barrier(0);   // keep next-tile loads above compute

        float* const ow0 = &ldso[wave][ln * 100];
#pragma unroll
        for (int tloc = 0; tloc < 4; ++tloc) {
            short8 xa[4];
            build_xa_ldsT(cur, tloc, vcl, q, xa);
            floatx16 y = compute_yt(xa, wf, af, q);
            // stage relu'd values: [o=ln][tloc*25 + w], w = 4q + 8g2 + j
            float* ow = ow0 + tloc * 25 + 4 * q;
#pragma unroll
            for (int g2 = 0; g2 < 3; ++g2) {
#pragma unroll
                for (int j = 0; j < 4; ++j) {
                    float v = sc * y[4 * g2 + j] + sh;
                    ow[8 * g2 + j] = v > 0.f ? v : 0.f;
                }
            }
            if (q == 0) {                      // w = 24  (reg 12)
                float v = sc * y[12] + sh;
                ow0[tloc * 25 + 24] = v > 0.f ? v : 0.f;
            }
        }

        if (g < NT / 4 - 1) {
            stage_commit(nxt, tid, sa, sb);  // loads landed under compute
            __syncthreads();
        }

        // flush this wave's 32o x 100 floats: 13 coalesced 16B-aligned dwordx4
        // (after the barrier: stores drain under the next tile's compute)
#pragma unroll
        for (int f = 0; f < 13; ++f) {
            int cid = f * 64 + lane;
            if (f < 12 || lane < 32) {
                int o = div25(cid);
                int c = cid - 25 * o;
                floatx4 v = *(const floatx4*)&ldso[wave][o * 100 + 4 * c];
                *(floatx4*)(ob + (size_t)o * (T_ * V_) + t4 * 25 + 4 * c) = v;
            }
        }

        uint32_t* t = cur; cur = nxt; nxt = t;
    }
}

// ---- stats are folded inside pass2; nothing else needed --------------------

extern "C" void kernel_launch(void* const* d_in, const int* in_sizes, int n_in,
                              void* d_out, int out_size, void* d_ws, size_t ws_size,
                              hipStream_t stream) {
    const float* x     = (const float*)d_in[0];
    const float* adj   = (const float*)d_in[1];
    const float* W     = (const float*)d_in[2];
    // d_in[3] = conv bias: cancelled exactly by training-mode BatchNorm -> unused
    const float* gamma = (const float*)d_in[4];
    const float* beta  = (const float*)d_in[5];
    float* out = (float*)d_out;

    float* psum = (float*)d_ws;
    float* psq  = (float*)((char*)d_ws + NSLOTS * COUT * sizeof(float));

    hipMemsetAsync(psum, 0, 2 * NSLOTS * COUT * sizeof(float), stream);

    dim3 grid(T_ / NT, B_);
    pass1_kernel<<<grid, 256, 0, stream>>>(x, adj, W, psum, psq);
    pass2_kernel<<<grid, 256, 0, stream>>>(x, adj, W, gamma, beta, psum, psq, out);
}